// Round 5
// baseline (11293.045 us; speedup 1.0000x reference)
//
#include <hip/hip_runtime.h>
#include <stdint.h>

// ---------------------------------------------------------------------------
// Encoder_Processor round 5: one-hop tensor-parallel pipeline.
// 7 levels x 8 shards (56 WGs x 512 thr). Each WG: full xt + full h in LDS
// (ping-pong), W/U slice split-K in regs, FULL W1 in regs (replicated h1/
// combine -> h never exchanged intra-level). Per step the ONLY exchange is
// the G1 slice broadcast (publish 8KB, gather 7x8KB, parity-double-buffered)
// + tiny z partials. Flags = raw sc0sc1 stores after vmcnt(0) (no RELEASE /
// L2-writeback). xt[t+1] staged via global_load_lds DMA (per-t-unique bufs).
// ---------------------------------------------------------------------------

typedef _Float16 f16x8 __attribute__((ext_vector_type(8)));
typedef float    f32x4 __attribute__((ext_vector_type(4)));
typedef unsigned int u32;

static constexpr int SS = 256, BB = 64, DIN = 256, DH = 256, DNN = 512, DA = 64;

// workspace layout (bytes)
static constexpr size_t OFF_FLAGS = 0;                         // u32[2048]
static constexpr size_t OFF_MASKT = 8192;                      // f32 [t][s] 64KB
static constexpr size_t OFF_WEMB  = OFF_MASKT + 65536;
static constexpr size_t OFF_W     = OFF_WEMB + (size_t)DIN * DH * 2;
static constexpr size_t OFF_U     = OFF_W + (size_t)DH * DNN * 2;
static constexpr size_t OFF_W1    = OFF_U + (size_t)DH * DNN * 2;
static constexpr size_t OFF_WA1   = OFF_W1 + (size_t)DNN * DH * 2;
static constexpr size_t OFF_UA1   = OFF_WA1 + (size_t)DH * DA * 2;
static constexpr size_t OFF_NM    = OFF_UA1 + (size_t)DH * DA * 2;  // 8 x 64KB
static constexpr size_t SZ_NM     = (size_t)SS * BB * 4;
static constexpr size_t OFF_HV    = OFF_NM + 8 * SZ_NM;
static constexpr size_t OFF_G1    = OFF_HV + 8 * SZ_NM;        // 8 lvl x 2 par x 64KB
static constexpr size_t SZ_G1     = (size_t)BB * DNN * 2;
static constexpr size_t OFF_Z     = OFF_G1 + 8 * 2 * SZ_G1;    // 8 x 2 x 1KB
static constexpr size_t OFF_HB    = (size_t)4 << 20;           // 8 x 8MB f16 frag [t][kq][s]
static constexpr size_t SZ_HB     = (size_t)SS * BB * DH * 2;
static constexpr size_t WS_NEEDED = OFF_HB + 8 * SZ_HB;        // ~68MB (same as r4)

__device__ __forceinline__ float lrelu(float v) { return v >= 0.0f ? v : 0.01f * v; }

// --- coherent (L1/L2-bypass, L3 point) asm ops; loads valid after vwait ----
__device__ __forceinline__ f32x4 ld128(const f32x4* p) {
  f32x4 r;
  asm volatile("global_load_dwordx4 %0, %1, off sc0 sc1" : "=v"(r) : "v"(p) : "memory");
  return r;
}
__device__ __forceinline__ void st128(f32x4* p, f32x4 v) {
  asm volatile("global_store_dwordx4 %0, %1, off sc0 sc1" :: "v"(p), "v"(v) : "memory");
}
__device__ __forceinline__ float ldf(const float* p) {
  float r;
  asm volatile("global_load_dword %0, %1, off sc0 sc1" : "=v"(r) : "v"(p) : "memory");
  return r;
}
__device__ __forceinline__ void stf(float* p, float v) {
  asm volatile("global_store_dword %0, %1, off sc0 sc1" :: "v"(p), "v"(v) : "memory");
}
__device__ __forceinline__ void stu(u32* p, u32 v) {
  asm volatile("global_store_dword %0, %1, off sc0 sc1" :: "v"(p), "v"(v) : "memory");
}
__device__ __forceinline__ u32 ldu(const u32* p) {
  u32 r;
  asm volatile("global_load_dword %0, %1, off sc0 sc1\n\ts_waitcnt vmcnt(0)"
               : "=v"(r) : "v"(p) : "memory");
  return r;
}
__device__ __forceinline__ void vwait() { asm volatile("s_waitcnt vmcnt(0)" ::: "memory"); }

__device__ __forceinline__ void poll1(const u32* p, u32 need) {
  #pragma nounroll
  for (int g = 0; g < (1 << 17); ++g) { if (ldu(p) >= need) return; }
}
// all 8 flags >= need (lane i checks flag i&7)
__device__ __forceinline__ void poll8(const u32* base, u32 need, int lane) {
  #pragma nounroll
  for (int g = 0; g < (1 << 17); ++g) {
    u32 v = ldu(base + (lane & 7));
    if (__all((int)(v >= need))) return;
  }
}

// async global->LDS DMA, 16B/lane; l must be the WAVE-UNIFORM base, g per-lane
__device__ __forceinline__ void dma16(const _Float16* g, _Float16* l) {
  auto* gp = (const __attribute__((address_space(1))) u32*)(uintptr_t)g;
  auto* lp = (__attribute__((address_space(3))) u32*)(uintptr_t)l;
  __builtin_amdgcn_global_load_lds(gp, lp, 16, 0, 0);
}

// ---------------------------------------------------------------------------
__global__ void zero_flags_k(u32* f) { f[threadIdx.x] = 0u; f[threadIdx.x + 1024] = 0u; }

__global__ void maskT_k(const float* __restrict__ mask, float* __restrict__ mT) {
  int idx = blockIdx.x * 256 + threadIdx.x;          // 16384
  int t = idx >> 6, s = idx & 63;
  mT[idx] = mask[(size_t)s * SS + t];
}

// pack fp32 row-major [K][N] into f16 MFMA B-frag order
__global__ void pack_weight_k(const float* __restrict__ src, _Float16* __restrict__ dst,
                              int K, int N) {
  int idx = blockIdx.x * 256 + threadIdx.x;
  if (idx >= K * N) return;
  int k = idx / N, n = idx - k * N;
  int kt = k >> 5, q = (k >> 3) & 3, jj = k & 7;
  int nt = n >> 4, l = n & 15;
  size_t p = (((size_t)(kt * (N >> 4) + nt) * 4 + q) * 16 + l) * 8 + jj;
  dst[p] = (_Float16)src[idx];
}

// ---------------------------------------------------------------------------
// embedding: xe = x@W_emb + b_emb -> level-0 h buffer, frag-linear f16
// ---------------------------------------------------------------------------
__global__ __launch_bounds__(512, 2) void emb_k(const float* __restrict__ xin,
                                                const float* __restrict__ b_emb,
                                                char* __restrict__ ws) {
  const int tid = threadIdx.x, wave = tid >> 6, lane = tid & 63;
  const int l15 = lane & 15, quad = lane >> 4;
  const _Float16* Wp = (const _Float16*)(ws + OFF_WEMB);
  _Float16* xe = (_Float16*)(ws + OFF_HB);

  f16x8 bE[16];
  #pragma unroll
  for (int kt = 0; kt < 8; ++kt)
    #pragma unroll
    for (int i = 0; i < 2; ++i)
      bE[kt * 2 + i] = *(const f16x8*)(Wp + (((size_t)(kt * 16 + (wave * 2 + i)) * 4 + quad) * 16 + l15) * 8);
  float ber[2] = { b_emb[(wave * 2) * 16 + l15], b_emb[(wave * 2 + 1) * 16 + l15] };

  __shared__ __align__(16) _Float16 xtF[32 * 65 * 8];
  __shared__ __align__(16) _Float16 oF[32 * 65 * 8];

  for (int tt = 0; tt < 4; ++tt) {
    const int t = (int)blockIdx.x + 64 * tt;
    #pragma unroll
    for (int c = 0; c < 4; ++c) {
      int u = tid + 512 * c, s = u >> 5, kg = u & 31;
      const float* src = xin + ((size_t)s * SS + t) * DIN + kg * 8;
      f32x4 v0 = *(const f32x4*)src, v1 = *(const f32x4*)(src + 4);
      f16x8 p;
      p[0]=(_Float16)v0[0]; p[1]=(_Float16)v0[1]; p[2]=(_Float16)v0[2]; p[3]=(_Float16)v0[3];
      p[4]=(_Float16)v1[0]; p[5]=(_Float16)v1[1]; p[6]=(_Float16)v1[2]; p[7]=(_Float16)v1[3];
      *(f16x8*)(xtF + ((size_t)kg * 65 + s) * 8) = p;
    }
    __syncthreads();
    f32x4 acc[2][4] = {};
    #pragma unroll
    for (int kt = 0; kt < 8; ++kt) {
      f16x8 ax[4];
      #pragma unroll
      for (int mt = 0; mt < 4; ++mt)
        ax[mt] = *(const f16x8*)(xtF + (((size_t)(kt * 4 + quad)) * 65 + (mt * 16 + l15)) * 8);
      #pragma unroll
      for (int i = 0; i < 2; ++i)
        #pragma unroll
        for (int mt = 0; mt < 4; ++mt)
          acc[i][mt] = __builtin_amdgcn_mfma_f32_16x16x32_f16(ax[mt], bE[kt * 2 + i], acc[i][mt], 0, 0, 0);
    }
    #pragma unroll
    for (int i = 0; i < 2; ++i) {
      int n = (wave * 2 + i) * 16 + l15;
      int kq = n >> 3, jn = n & 7;
      #pragma unroll
      for (int mt = 0; mt < 4; ++mt)
        #pragma unroll
        for (int r = 0; r < 4; ++r) {
          int s = mt * 16 + quad * 4 + r;
          oF[((size_t)kq * 65 + s) * 8 + jn] = (_Float16)(acc[i][mt][r] + ber[i]);
        }
    }
    __syncthreads();
    #pragma unroll
    for (int c = 0; c < 4; ++c) {
      int u = tid + 512 * c, kq = u >> 6, s = u & 63;
      f32x4 v = *(const f32x4*)(oF + ((size_t)kq * 65 + s) * 8);
      *((f32x4*)(xe + (((size_t)t * 32 + kq) * 64 + s) * 8)) = v;  // plain; kernel-end flush
    }
    __syncthreads();
  }
}

// ---------------------------------------------------------------------------
// pipeline: 56 WGs (7 levels x 8 shards) x 512 thr
// ---------------------------------------------------------------------------
__global__ __launch_bounds__(512, 2) void pipe_k(
    const float* __restrict__ b_in, const float* __restrict__ b1v,
    const float* __restrict__ bA1, const float* __restrict__ WA3,
    const float* __restrict__ bA3, char* __restrict__ ws,
    float* __restrict__ outp) {
  const int level = 1 + ((int)blockIdx.x >> 3);
  const int j     = (int)blockIdx.x & 7;
  const int tid   = threadIdx.x, wave = tid >> 6, lane = tid & 63;
  const int l15   = lane & 15, quad = lane >> 4;
  const int khalf = wave >> 2, ntL = wave & 3;    // D split-K roles

  u32* flags = (u32*)(ws + OFF_FLAGS);
  u32* gfl   = flags + level * 16;                // G1 flags [8]
  u32* hfl   = flags + 256 + level * 16;          // own h flags [8]
  u32* hflP  = flags + 256 + (level - 1) * 16;    // prev-level h flags [8]

  const _Float16* Wp   = (const _Float16*)(ws + OFF_W);
  const _Float16* Up   = (const _Float16*)(ws + OFF_U);
  const _Float16* W1p  = (const _Float16*)(ws + OFF_W1);
  const _Float16* WA1p = (const _Float16*)(ws + OFF_WA1);
  const _Float16* UA1p = (const _Float16*)(ws + OFF_UA1);
  const float*    maskT = (const float*)(ws + OFF_MASKT);

  const _Float16* xsrc = (const _Float16*)(ws + OFF_HB) + (size_t)(level - 1) * SS * BB * DH;
  _Float16* hdst = (level < 7) ? (_Float16*)(ws + OFF_HB) + (size_t)level * SS * BB * DH : nullptr;
  _Float16* g1g  = (_Float16*)(ws + OFF_G1) + (size_t)level * 2 * BB * DNN;   // 2 parities
  float*    zg   = (float*)(ws + OFF_Z) + (size_t)level * 512;                // 2 x 256
  float*    nmW  = (float*)(ws + OFF_NM + (size_t)level * SZ_NM);
  float*    hvW  = (float*)(ws + OFF_HV + (size_t)level * SZ_NM);
  const float* nmR = (const float*)(ws + OFF_NM + (size_t)(level - 1) * SZ_NM);
  const float* hvR = (const float*)(ws + OFF_HV + (size_t)(level - 1) * SZ_NM);

  // --- weights in registers ---
  f16x8 bW[4], bU[4];                 // D: n-tile j*4+ntL, k-half khalf
  #pragma unroll
  for (int i = 0; i < 4; ++i) {
    int kt = khalf * 4 + i;
    bW[i] = *(const f16x8*)(Wp + (((size_t)(kt * 32 + j * 4 + ntL) * 4 + quad) * 16 + l15) * 8);
    bU[i] = *(const f16x8*)(Up + (((size_t)(kt * 32 + j * 4 + ntL) * 4 + quad) * 16 + l15) * 8);
  }
  f16x8 b1f[2][16];                   // FULL W1: wave w -> nt1 {2w, 2w+1}
  #pragma unroll
  for (int h2 = 0; h2 < 2; ++h2)
    #pragma unroll
    for (int kt = 0; kt < 16; ++kt)
      b1f[h2][kt] = *(const f16x8*)(W1p + (((size_t)(kt * 16 + wave * 2 + h2) * 4 + quad) * 16 + l15) * 8);

  const float birD = b_in[j * 64 + ntL * 16 + l15];
  const float b1r0 = b1v[(wave * 2) * 16 + l15];
  const float b1r1 = b1v[(wave * 2 + 1) * 16 + l15];
  const float ba1r = bA1[(j & 3) * 16 + l15];
  const float wa3r = WA3[(j & 3) * 16 + l15];
  const float bA3v = bA3[0];

  // --- LDS (146KB) ---
  __shared__ __align__(16) _Float16 bufA[32 * 64 * 8];   // 32KB ping
  __shared__ __align__(16) _Float16 bufB[32 * 64 * 8];   // 32KB pong
  __shared__ __align__(16) _Float16 g1F[64 * 64 * 8];    // 64KB full G1 (+D scratch overlay)
  __shared__ __align__(16) _Float16 waF[16 * 64 * 8];    // 16KB action b-frags
  __shared__ float zarr[256], nmA[64], hvA[64];
  __shared__ float gB[64], gX[64], gH[64], gHv[64];

  if (j < 4) {
    for (int u = tid; u < 1024; u += 512) {
      int ktm = u >> 6, lu = u & 63, kt = ktm >> 1, m = ktm & 1;
      const _Float16* sp = (m ? UA1p : WA1p) +
          (((size_t)(kt * 4 + j) * 4 + (lu >> 4)) * 16 + (lu & 15)) * 8;
      *(f16x8*)(waF + (size_t)u * 8) = *(const f16x8*)sp;
    }
  }
  #pragma unroll
  for (int c = 0; c < 4; ++c) ((f32x4*)bufB)[tid + 512 * c] = f32x4{0.f, 0.f, 0.f, 0.f};
  if (tid < 64) gHv[tid] = 0.0f;
  float hreg[2][4][4] = {};

  // prologue: stage xt[0] into bufA (DMA; h buffers are per-t-unique)
  if (level >= 2 && wave == 0) poll8(hflP, 1, lane);
  __syncthreads();
  #pragma unroll
  for (int c = 0; c < 4; ++c) {
    int ub = wave * 256 + c * 64;   // wave-uniform base unit
    dma16(xsrc + (size_t)(ub + lane) * 8, bufA + (size_t)ub * 8);
  }
  vwait();
  __syncthreads();

  for (int t = 0; t < SS; ++t) {
    const int par = t & 1;
    _Float16* bufX = par ? bufB : bufA;   // xt[t]
    _Float16* bufH = par ? bufA : bufB;   // h[t-1]  (becomes xt[t+1] dest)
    _Float16* g1p  = g1g + (size_t)par * BB * DNN;
    float*    zp   = zg + par * 256;

    // ---- D: G1 slice (split-K) + action partials ----
    f32x4 dacc[4] = {};
    f32x4 aacc = {0.f, 0.f, 0.f, 0.f};
    #pragma unroll
    for (int i = 0; i < 4; ++i) {
      int kq = (khalf * 4 + i) * 4 + quad;
      f16x8 ax[4], ah[4];
      #pragma unroll
      for (int mt = 0; mt < 4; ++mt) {
        ax[mt] = *(const f16x8*)(bufX + ((size_t)kq * 64 + mt * 16 + l15) * 8);
        ah[mt] = *(const f16x8*)(bufH + ((size_t)kq * 64 + mt * 16 + l15) * 8);
      }
      #pragma unroll
      for (int mt = 0; mt < 4; ++mt) {
        dacc[mt] = __builtin_amdgcn_mfma_f32_16x16x32_f16(ax[mt], bW[i], dacc[mt], 0, 0, 0);
        dacc[mt] = __builtin_amdgcn_mfma_f32_16x16x32_f16(ah[mt], bU[i], dacc[mt], 0, 0, 0);
      }
      if (j < 4) {  // action: cols [16j,16j+16), m-tile ntL, k-half khalf
        f16x8 bWa = *(const f16x8*)(waF + ((size_t)((khalf * 4 + i) * 2) * 64 + lane) * 8);
        f16x8 bUa = *(const f16x8*)(waF + ((size_t)((khalf * 4 + i) * 2 + 1) * 64 + lane) * 8);
        aacc = __builtin_amdgcn_mfma_f32_16x16x32_f16(ax[ntL], bWa, aacc, 0, 0, 0);
        aacc = __builtin_amdgcn_mfma_f32_16x16x32_f16(ah[ntL], bUa, aacc, 0, 0, 0);
      }
    }
    // split-K reduce via scratch overlay on peer regions of g1F
    {
      f32x4* scr = (f32x4*)g1F;
      const int slotWU = ((j + 1 + (ntL >> 1)) & 7);
      if (khalf) {
        #pragma unroll
        for (int mt = 0; mt < 4; ++mt)
          scr[slotWU * 512 + (ntL & 1) * 256 + mt * 64 + lane] = dacc[mt];
        if (j < 4) scr[((j + 3) & 7) * 512 + ntL * 64 + lane] = aacc;
      }
      __syncthreads();
      if (!khalf) {
        const int n = j * 64 + ntL * 16 + l15, kqG = n >> 3, jn = n & 7;
        #pragma unroll
        for (int mt = 0; mt < 4; ++mt) {
          f32x4 o = scr[slotWU * 512 + (ntL & 1) * 256 + mt * 64 + lane];
          #pragma unroll
          for (int r = 0; r < 4; ++r) {
            float g = lrelu(dacc[mt][r] + o[r] + birD);
            g1F[((size_t)kqG * 64 + mt * 16 + quad * 4 + r) * 8 + jn] = (_Float16)g;
          }
        }
        if (j < 4) {
          f32x4 o = scr[((j + 3) & 7) * 512 + ntL * 64 + lane];
          #pragma unroll
          for (int r = 0; r < 4; ++r) {
            float a = lrelu(aacc[r] + o[r] + ba1r) * wa3r;
            a += __shfl_xor(a, 1); a += __shfl_xor(a, 2);
            a += __shfl_xor(a, 4); a += __shfl_xor(a, 8);
            if (l15 == 0) zarr[j * 64 + ntL * 16 + quad * 4 + r] = a;
          }
        }
      }
    }
    __syncthreads();

    // ---- publish own G1 slice (+z) ----
    {
      f32x4 v = ((const f32x4*)g1F)[j * 512 + tid];
      st128((f32x4*)g1p + j * 512 + tid, v);
      if (j < 4 && tid < 64) stf(zp + j * 64 + tid, zarr[j * 64 + tid]);
    }
    vwait();
    __syncthreads();
    if (tid == 0) stu(gfl + j, (u32)(t + 1));

    // ---- gather peer G1 slices; wave j does cross-level plumbing ----
    if (wave != j) {
      poll1(gfl + wave, (u32)(t + 1));
      const f32x4* src = (const f32x4*)g1p + wave * 512;
      f32x4 g4[8];
      #pragma unroll
      for (int it = 0; it < 8; ++it) g4[it] = ld128(src + it * 64 + lane);
      float zv = 0.0f;
      if (wave < 4) zv = ldf(zp + wave * 64 + lane);
      vwait();
      #pragma unroll
      for (int it = 0; it < 8; ++it) ((f32x4*)g1F)[wave * 512 + it * 64 + lane] = g4[it];
      if (wave < 4) zarr[wave * 64 + lane] = zv;
    } else {
      if (level >= 2) {
        u32 need = (u32)((t + 2 <= SS) ? (t + 2) : SS);
        poll8(hflP, need, lane);
        float nmv = ldf(nmR + (size_t)((t + 1 < SS) ? (t + 1) : (SS - 1)) * 64 + lane);
        float hvv = ldf(hvR + (size_t)t * 64 + lane);
        vwait();
        nmA[lane] = nmv; hvA[lane] = hvv;
      } else {
        float mv = maskT[(size_t)t * 64 + lane];
        nmA[lane] = mv; hvA[lane] = mv;
      }
    }
    __syncthreads();

    // ---- xt[t+1] DMA (off critical path; drained at step end) ----
    if (t + 1 < SS) {
      const _Float16* src = xsrc + (size_t)(t + 1) * BB * DH;
      #pragma unroll
      for (int c = 0; c < 4; ++c) {
        int ub = wave * 256 + c * 64;
        dma16(src + (size_t)(ub + lane) * 8, bufH + (size_t)ub * 8);
      }
    }
    // ---- gates (wave 0) ----
    if (wave == 0) {
      int s = lane;
      float z   = bA3v + zarr[s] + zarr[64 + s] + zarr[128 + s] + zarr[192 + s];
      float nm0 = fminf(fmaxf(0.2f * z + 0.5f, 0.0f), 1.0f);
      float pm  = (level >= 2 && t + 1 >= SS) ? 1.0f : nmA[s];
      float phv = hvA[s];
      float lv  = (t == SS - 1) ? 1.0f : 0.0f;
      float nm  = (1.0f - lv) * (pm * phv * nm0);
      float hvp = gHv[s], omn = 1.0f - nm;
      float both = pm * phv * omn * hvp;
      float xo   = pm * phv * (nm + omn * (1.0f - hvp));
      float ho   = (1.0f - pm * phv) * omn * hvp;
      float hv   = both + xo + ho;
      gB[s] = both; gX[s] = xo; gH[s] = ho; gHv[s] = hv;
      if (level < 7) {
        stf(nmW + (size_t)t * 64 + s, nm);
        stf(hvW + (size_t)t * 64 + s, hv);
      }
    }
    __syncthreads();

    // ---- H: full h1 = lrelu(G1@W1+b1) (replicated); combine in place ----
    f32x4 c1[2][4] = {};
    #pragma unroll
    for (int kt = 0; kt < 16; ++kt) {
      int kq = kt * 4 + quad;
      f16x8 ag[4];
      #pragma unroll
      for (int mt = 0; mt < 4; ++mt)
        ag[mt] = *(const f16x8*)(g1F + ((size_t)kq * 64 + mt * 16 + l15) * 8);
      #pragma unroll
      for (int h2 = 0; h2 < 2; ++h2)
        #pragma unroll
        for (int mt = 0; mt < 4; ++mt)
          c1[h2][mt] = __builtin_amdgcn_mfma_f32_16x16x32_f16(ag[mt], b1f[h2][kt], c1[h2][mt], 0, 0, 0);
    }
    #pragma unroll
    for (int h2 = 0; h2 < 2; ++h2) {
      const int n = (wave * 2 + h2) * 16 + l15, kqc = n >> 3, jc = n & 7;
      const float b1r = h2 ? b1r1 : b1r0;
      #pragma unroll
      for (int mt = 0; mt < 4; ++mt)
        #pragma unroll
        for (int r = 0; r < 4; ++r) {
          int s = mt * 16 + quad * 4 + r;
          float h1  = lrelu(c1[h2][mt][r] + b1r);
          float xtv = (float)bufX[((size_t)kqc * 64 + s) * 8 + jc];
          float hn  = gB[s] * h1 + gX[s] * xtv + gH[s] * hreg[h2][mt][r];
          hreg[h2][mt][r] = hn;
          bufX[((size_t)kqc * 64 + s) * 8 + jc] = (_Float16)hn;   // in place
          if (level == 7 && t == SS - 1) outp[(size_t)s * DH + n] = hn;
        }
    }
    __syncthreads();

    // ---- publish own h slice (cross-level) ----
    if (level < 7 && tid < 256) {
      f32x4 v = ((const f32x4*)bufX)[j * 256 + tid];
      st128((f32x4*)(hdst + (size_t)t * BB * DH) + j * 256 + tid, v);
    }
    vwait();                 // drains h publish + nm/hv + xt DMA (all waves)
    __syncthreads();
    if (level < 7 && tid == 0) stu(hfl + j, (u32)(t + 1));
  }
}

// ---------------------------------------------------------------------------
extern "C" void kernel_launch(void* const* d_in, const int* in_sizes, int n_in,
                              void* d_out, int out_size, void* d_ws, size_t ws_size,
                              hipStream_t stream) {
  const float* x     = (const float*)d_in[0];
  const float* mask  = (const float*)d_in[1];
  const float* W_emb = (const float*)d_in[3];
  const float* b_emb = (const float*)d_in[4];
  const float* W     = (const float*)d_in[5];
  const float* U     = (const float*)d_in[6];
  const float* b     = (const float*)d_in[7];
  const float* W1    = (const float*)d_in[8];
  const float* b1    = (const float*)d_in[9];
  const float* WA1   = (const float*)d_in[10];
  const float* UA1   = (const float*)d_in[11];
  const float* bA1   = (const float*)d_in[12];
  const float* WA3   = (const float*)d_in[13];
  const float* bA3   = (const float*)d_in[14];
  char* ws = (char*)d_ws;

  if (ws_size < WS_NEEDED) return;

  zero_flags_k<<<1, 1024, 0, stream>>>((u32*)(ws + OFF_FLAGS));
  maskT_k<<<64, 256, 0, stream>>>(mask, (float*)(ws + OFF_MASKT));
  pack_weight_k<<<(DIN * DH + 255) / 256, 256, 0, stream>>>(W_emb, (_Float16*)(ws + OFF_WEMB), DIN, DH);
  pack_weight_k<<<(DH * DNN + 255) / 256, 256, 0, stream>>>(W, (_Float16*)(ws + OFF_W), DH, DNN);
  pack_weight_k<<<(DH * DNN + 255) / 256, 256, 0, stream>>>(U, (_Float16*)(ws + OFF_U), DH, DNN);
  pack_weight_k<<<(DNN * DH + 255) / 256, 256, 0, stream>>>(W1, (_Float16*)(ws + OFF_W1), DNN, DH);
  pack_weight_k<<<(DH * DA + 255) / 256, 256, 0, stream>>>(WA1, (_Float16*)(ws + OFF_WA1), DH, DA);
  pack_weight_k<<<(DH * DA + 255) / 256, 256, 0, stream>>>(UA1, (_Float16*)(ws + OFF_UA1), DH, DA);

  emb_k<<<64, 512, 0, stream>>>(x, b_emb, ws);
  pipe_k<<<56, 512, 0, stream>>>(b, b1, bA1, WA3, bA3, ws, (float*)d_out);
}

// Round 6
// 11271.389 us; speedup vs baseline: 1.0019x; 1.0019x over previous
//
#include <hip/hip_runtime.h>
#include <stdint.h>

// ---------------------------------------------------------------------------
// Encoder_Processor round 6: one-hop tensor-parallel pipeline (r5 structure)
// with the register-spill fix: __launch_bounds__(512, 1) -> 256 VGPRs/thread,
// so the replicated W1 fragments stay register-resident (r5's (512,2) capped
// at 128 VGPRs and silently spilled W1 to scratch -> 3x regression).
// 7 levels x 8 shards (56 WGs x 512 thr). Each WG: full xt + full h in LDS
// (ping-pong), W/U slice split-K in regs, FULL W1 in regs. Per step the ONLY
// exchange is the G1 slice broadcast + tiny z partials. Flags = raw sc0sc1
// stores after vmcnt(0). xt[t+1] staged via global_load_lds DMA.
// ---------------------------------------------------------------------------

typedef _Float16 f16x8 __attribute__((ext_vector_type(8)));
typedef float    f32x4 __attribute__((ext_vector_type(4)));
typedef unsigned int u32;

static constexpr int SS = 256, BB = 64, DIN = 256, DH = 256, DNN = 512, DA = 64;

// workspace layout (bytes)
static constexpr size_t OFF_FLAGS = 0;                         // u32[2048]
static constexpr size_t OFF_MASKT = 8192;                      // f32 [t][s] 64KB
static constexpr size_t OFF_WEMB  = OFF_MASKT + 65536;
static constexpr size_t OFF_W     = OFF_WEMB + (size_t)DIN * DH * 2;
static constexpr size_t OFF_U     = OFF_W + (size_t)DH * DNN * 2;
static constexpr size_t OFF_W1    = OFF_U + (size_t)DH * DNN * 2;
static constexpr size_t OFF_WA1   = OFF_W1 + (size_t)DNN * DH * 2;
static constexpr size_t OFF_UA1   = OFF_WA1 + (size_t)DH * DA * 2;
static constexpr size_t OFF_NM    = OFF_UA1 + (size_t)DH * DA * 2;  // 8 x 64KB
static constexpr size_t SZ_NM     = (size_t)SS * BB * 4;
static constexpr size_t OFF_HV    = OFF_NM + 8 * SZ_NM;
static constexpr size_t OFF_G1    = OFF_HV + 8 * SZ_NM;        // 8 lvl x 2 par x 64KB
static constexpr size_t SZ_G1     = (size_t)BB * DNN * 2;
static constexpr size_t OFF_Z     = OFF_G1 + 8 * 2 * SZ_G1;    // 8 x 2 x 1KB
static constexpr size_t OFF_HB    = (size_t)4 << 20;           // 8 x 8MB f16 frag [t][kq][s]
static constexpr size_t SZ_HB     = (size_t)SS * BB * DH * 2;
static constexpr size_t WS_NEEDED = OFF_HB + 8 * SZ_HB;

__device__ __forceinline__ float lrelu(float v) { return v >= 0.0f ? v : 0.01f * v; }

// --- coherent (L1/L2-bypass, L3 point) asm ops; loads valid after vwait ----
__device__ __forceinline__ f32x4 ld128(const f32x4* p) {
  f32x4 r;
  asm volatile("global_load_dwordx4 %0, %1, off sc0 sc1" : "=v"(r) : "v"(p) : "memory");
  return r;
}
__device__ __forceinline__ void st128(f32x4* p, f32x4 v) {
  asm volatile("global_store_dwordx4 %0, %1, off sc0 sc1" :: "v"(p), "v"(v) : "memory");
}
__device__ __forceinline__ float ldf(const float* p) {
  float r;
  asm volatile("global_load_dword %0, %1, off sc0 sc1" : "=v"(r) : "v"(p) : "memory");
  return r;
}
__device__ __forceinline__ void stf(float* p, float v) {
  asm volatile("global_store_dword %0, %1, off sc0 sc1" :: "v"(p), "v"(v) : "memory");
}
__device__ __forceinline__ void stu(u32* p, u32 v) {
  asm volatile("global_store_dword %0, %1, off sc0 sc1" :: "v"(p), "v"(v) : "memory");
}
__device__ __forceinline__ u32 ldu(const u32* p) {
  u32 r;
  asm volatile("global_load_dword %0, %1, off sc0 sc1\n\ts_waitcnt vmcnt(0)"
               : "=v"(r) : "v"(p) : "memory");
  return r;
}
__device__ __forceinline__ void vwait() { asm volatile("s_waitcnt vmcnt(0)" ::: "memory"); }

__device__ __forceinline__ void poll1(const u32* p, u32 need) {
  #pragma nounroll
  for (int g = 0; g < (1 << 17); ++g) { if (ldu(p) >= need) return; }
}
// all 8 flags >= need (lane i checks flag i&7)
__device__ __forceinline__ void poll8(const u32* base, u32 need, int lane) {
  #pragma nounroll
  for (int g = 0; g < (1 << 17); ++g) {
    u32 v = ldu(base + (lane & 7));
    if (__all((int)(v >= need))) return;
  }
}

// async global->LDS DMA, 16B/lane; l must be the WAVE-UNIFORM base, g per-lane
__device__ __forceinline__ void dma16(const _Float16* g, _Float16* l) {
  auto* gp = (const __attribute__((address_space(1))) u32*)(uintptr_t)g;
  auto* lp = (__attribute__((address_space(3))) u32*)(uintptr_t)l;
  __builtin_amdgcn_global_load_lds(gp, lp, 16, 0, 0);
}

// ---------------------------------------------------------------------------
__global__ void zero_flags_k(u32* f) { f[threadIdx.x] = 0u; f[threadIdx.x + 1024] = 0u; }

__global__ void maskT_k(const float* __restrict__ mask, float* __restrict__ mT) {
  int idx = blockIdx.x * 256 + threadIdx.x;          // 16384
  int t = idx >> 6, s = idx & 63;
  mT[idx] = mask[(size_t)s * SS + t];
}

// pack fp32 row-major [K][N] into f16 MFMA B-frag order
__global__ void pack_weight_k(const float* __restrict__ src, _Float16* __restrict__ dst,
                              int K, int N) {
  int idx = blockIdx.x * 256 + threadIdx.x;
  if (idx >= K * N) return;
  int k = idx / N, n = idx - k * N;
  int kt = k >> 5, q = (k >> 3) & 3, jj = k & 7;
  int nt = n >> 4, l = n & 15;
  size_t p = (((size_t)(kt * (N >> 4) + nt) * 4 + q) * 16 + l) * 8 + jj;
  dst[p] = (_Float16)src[idx];
}

// ---------------------------------------------------------------------------
// embedding: xe = x@W_emb + b_emb -> level-0 h buffer, frag-linear f16
// ---------------------------------------------------------------------------
__global__ __launch_bounds__(512, 2) void emb_k(const float* __restrict__ xin,
                                                const float* __restrict__ b_emb,
                                                char* __restrict__ ws) {
  const int tid = threadIdx.x, wave = tid >> 6, lane = tid & 63;
  const int l15 = lane & 15, quad = lane >> 4;
  const _Float16* Wp = (const _Float16*)(ws + OFF_WEMB);
  _Float16* xe = (_Float16*)(ws + OFF_HB);

  f16x8 bE[16];
  #pragma unroll
  for (int kt = 0; kt < 8; ++kt)
    #pragma unroll
    for (int i = 0; i < 2; ++i)
      bE[kt * 2 + i] = *(const f16x8*)(Wp + (((size_t)(kt * 16 + (wave * 2 + i)) * 4 + quad) * 16 + l15) * 8);
  float ber[2] = { b_emb[(wave * 2) * 16 + l15], b_emb[(wave * 2 + 1) * 16 + l15] };

  __shared__ __align__(16) _Float16 xtF[32 * 65 * 8];
  __shared__ __align__(16) _Float16 oF[32 * 65 * 8];

  for (int tt = 0; tt < 4; ++tt) {
    const int t = (int)blockIdx.x + 64 * tt;
    #pragma unroll
    for (int c = 0; c < 4; ++c) {
      int u = tid + 512 * c, s = u >> 5, kg = u & 31;
      const float* src = xin + ((size_t)s * SS + t) * DIN + kg * 8;
      f32x4 v0 = *(const f32x4*)src, v1 = *(const f32x4*)(src + 4);
      f16x8 p;
      p[0]=(_Float16)v0[0]; p[1]=(_Float16)v0[1]; p[2]=(_Float16)v0[2]; p[3]=(_Float16)v0[3];
      p[4]=(_Float16)v1[0]; p[5]=(_Float16)v1[1]; p[6]=(_Float16)v1[2]; p[7]=(_Float16)v1[3];
      *(f16x8*)(xtF + ((size_t)kg * 65 + s) * 8) = p;
    }
    __syncthreads();
    f32x4 acc[2][4] = {};
    #pragma unroll
    for (int kt = 0; kt < 8; ++kt) {
      f16x8 ax[4];
      #pragma unroll
      for (int mt = 0; mt < 4; ++mt)
        ax[mt] = *(const f16x8*)(xtF + (((size_t)(kt * 4 + quad)) * 65 + (mt * 16 + l15)) * 8);
      #pragma unroll
      for (int i = 0; i < 2; ++i)
        #pragma unroll
        for (int mt = 0; mt < 4; ++mt)
          acc[i][mt] = __builtin_amdgcn_mfma_f32_16x16x32_f16(ax[mt], bE[kt * 2 + i], acc[i][mt], 0, 0, 0);
    }
    #pragma unroll
    for (int i = 0; i < 2; ++i) {
      int n = (wave * 2 + i) * 16 + l15;
      int kq = n >> 3, jn = n & 7;
      #pragma unroll
      for (int mt = 0; mt < 4; ++mt)
        #pragma unroll
        for (int r = 0; r < 4; ++r) {
          int s = mt * 16 + quad * 4 + r;
          oF[((size_t)kq * 65 + s) * 8 + jn] = (_Float16)(acc[i][mt][r] + ber[i]);
        }
    }
    __syncthreads();
    #pragma unroll
    for (int c = 0; c < 4; ++c) {
      int u = tid + 512 * c, kq = u >> 6, s = u & 63;
      f32x4 v = *(const f32x4*)(oF + ((size_t)kq * 65 + s) * 8);
      *((f32x4*)(xe + (((size_t)t * 32 + kq) * 64 + s) * 8)) = v;  // plain; kernel-end flush
    }
    __syncthreads();
  }
}

// ---------------------------------------------------------------------------
// pipeline: 56 WGs (7 levels x 8 shards) x 512 thr, 1 block/CU, 256 VGPR cap
// ---------------------------------------------------------------------------
__global__ __launch_bounds__(512, 1) void pipe_k(
    const float* __restrict__ b_in, const float* __restrict__ b1v,
    const float* __restrict__ bA1, const float* __restrict__ WA3,
    const float* __restrict__ bA3, char* __restrict__ ws,
    float* __restrict__ outp) {
  const int level = 1 + ((int)blockIdx.x >> 3);
  const int j     = (int)blockIdx.x & 7;
  const int tid   = threadIdx.x, wave = tid >> 6, lane = tid & 63;
  const int l15   = lane & 15, quad = lane >> 4;
  const int khalf = wave >> 2, ntL = wave & 3;    // D split-K roles

  u32* flags = (u32*)(ws + OFF_FLAGS);
  u32* gfl   = flags + level * 16;                // G1 flags [8]
  u32* hfl   = flags + 256 + level * 16;          // own h flags [8]
  u32* hflP  = flags + 256 + (level - 1) * 16;    // prev-level h flags [8]

  const _Float16* Wp   = (const _Float16*)(ws + OFF_W);
  const _Float16* Up   = (const _Float16*)(ws + OFF_U);
  const _Float16* W1p  = (const _Float16*)(ws + OFF_W1);
  const _Float16* WA1p = (const _Float16*)(ws + OFF_WA1);
  const _Float16* UA1p = (const _Float16*)(ws + OFF_UA1);
  const float*    maskT = (const float*)(ws + OFF_MASKT);

  const _Float16* xsrc = (const _Float16*)(ws + OFF_HB) + (size_t)(level - 1) * SS * BB * DH;
  _Float16* hdst = (level < 7) ? (_Float16*)(ws + OFF_HB) + (size_t)level * SS * BB * DH : nullptr;
  _Float16* g1g  = (_Float16*)(ws + OFF_G1) + (size_t)level * 2 * BB * DNN;   // 2 parities
  float*    zg   = (float*)(ws + OFF_Z) + (size_t)level * 512;                // 2 x 256
  float*    nmW  = (float*)(ws + OFF_NM + (size_t)level * SZ_NM);
  float*    hvW  = (float*)(ws + OFF_HV + (size_t)level * SZ_NM);
  const float* nmR = (const float*)(ws + OFF_NM + (size_t)(level - 1) * SZ_NM);
  const float* hvR = (const float*)(ws + OFF_HV + (size_t)(level - 1) * SZ_NM);

  // --- weights in registers ---
  f16x8 bW[4], bU[4];                 // D: n-tile j*4+ntL, k-half khalf
  #pragma unroll
  for (int i = 0; i < 4; ++i) {
    int kt = khalf * 4 + i;
    bW[i] = *(const f16x8*)(Wp + (((size_t)(kt * 32 + j * 4 + ntL) * 4 + quad) * 16 + l15) * 8);
    bU[i] = *(const f16x8*)(Up + (((size_t)(kt * 32 + j * 4 + ntL) * 4 + quad) * 16 + l15) * 8);
  }
  f16x8 b1f[2][16];                   // FULL W1: wave w -> nt1 {2w, 2w+1}
  #pragma unroll
  for (int h2 = 0; h2 < 2; ++h2)
    #pragma unroll
    for (int kt = 0; kt < 16; ++kt)
      b1f[h2][kt] = *(const f16x8*)(W1p + (((size_t)(kt * 16 + wave * 2 + h2) * 4 + quad) * 16 + l15) * 8);

  const float birD = b_in[j * 64 + ntL * 16 + l15];
  const float b1r0 = b1v[(wave * 2) * 16 + l15];
  const float b1r1 = b1v[(wave * 2 + 1) * 16 + l15];
  const float ba1r = bA1[(j & 3) * 16 + l15];
  const float wa3r = WA3[(j & 3) * 16 + l15];
  const float bA3v = bA3[0];

  // --- LDS (146KB) ---
  __shared__ __align__(16) _Float16 bufA[32 * 64 * 8];   // 32KB ping
  __shared__ __align__(16) _Float16 bufB[32 * 64 * 8];   // 32KB pong
  __shared__ __align__(16) _Float16 g1F[64 * 64 * 8];    // 64KB full G1 (+D scratch overlay)
  __shared__ __align__(16) _Float16 waF[16 * 64 * 8];    // 16KB action b-frags
  __shared__ float zarr[256], nmA[64], hvA[64];
  __shared__ float gB[64], gX[64], gH[64], gHv[64];

  if (j < 4) {
    for (int u = tid; u < 1024; u += 512) {
      int ktm = u >> 6, lu = u & 63, kt = ktm >> 1, m = ktm & 1;
      const _Float16* sp = (m ? UA1p : WA1p) +
          (((size_t)(kt * 4 + j) * 4 + (lu >> 4)) * 16 + (lu & 15)) * 8;
      *(f16x8*)(waF + (size_t)u * 8) = *(const f16x8*)sp;
    }
  }
  #pragma unroll
  for (int c = 0; c < 4; ++c) ((f32x4*)bufB)[tid + 512 * c] = f32x4{0.f, 0.f, 0.f, 0.f};
  if (tid < 64) gHv[tid] = 0.0f;
  float hreg[2][4][4] = {};

  // prologue: stage xt[0] into bufA (DMA; h buffers are per-t-unique)
  if (level >= 2 && wave == 0) poll8(hflP, 1, lane);
  __syncthreads();
  #pragma unroll
  for (int c = 0; c < 4; ++c) {
    int ub = wave * 256 + c * 64;   // wave-uniform base unit
    dma16(xsrc + (size_t)(ub + lane) * 8, bufA + (size_t)ub * 8);
  }
  vwait();
  __syncthreads();

  for (int t = 0; t < SS; ++t) {
    const int par = t & 1;
    _Float16* bufX = par ? bufB : bufA;   // xt[t]
    _Float16* bufH = par ? bufA : bufB;   // h[t-1]  (becomes xt[t+1] dest)
    _Float16* g1p  = g1g + (size_t)par * BB * DNN;
    float*    zp   = zg + par * 256;

    // ---- D: G1 slice (split-K) + action partials ----
    f32x4 dacc[4] = {};
    f32x4 aacc = {0.f, 0.f, 0.f, 0.f};
    #pragma unroll
    for (int i = 0; i < 4; ++i) {
      int kq = (khalf * 4 + i) * 4 + quad;
      f16x8 ax[4], ah[4];
      #pragma unroll
      for (int mt = 0; mt < 4; ++mt) {
        ax[mt] = *(const f16x8*)(bufX + ((size_t)kq * 64 + mt * 16 + l15) * 8);
        ah[mt] = *(const f16x8*)(bufH + ((size_t)kq * 64 + mt * 16 + l15) * 8);
      }
      #pragma unroll
      for (int mt = 0; mt < 4; ++mt) {
        dacc[mt] = __builtin_amdgcn_mfma_f32_16x16x32_f16(ax[mt], bW[i], dacc[mt], 0, 0, 0);
        dacc[mt] = __builtin_amdgcn_mfma_f32_16x16x32_f16(ah[mt], bU[i], dacc[mt], 0, 0, 0);
      }
      if (j < 4) {  // action: cols [16j,16j+16), m-tile ntL, k-half khalf
        f16x8 bWa = *(const f16x8*)(waF + ((size_t)((khalf * 4 + i) * 2) * 64 + lane) * 8);
        f16x8 bUa = *(const f16x8*)(waF + ((size_t)((khalf * 4 + i) * 2 + 1) * 64 + lane) * 8);
        aacc = __builtin_amdgcn_mfma_f32_16x16x32_f16(ax[ntL], bWa, aacc, 0, 0, 0);
        aacc = __builtin_amdgcn_mfma_f32_16x16x32_f16(ah[ntL], bUa, aacc, 0, 0, 0);
      }
    }
    // split-K reduce via scratch overlay on peer regions of g1F
    {
      f32x4* scr = (f32x4*)g1F;
      const int slotWU = ((j + 1 + (ntL >> 1)) & 7);
      if (khalf) {
        #pragma unroll
        for (int mt = 0; mt < 4; ++mt)
          scr[slotWU * 512 + (ntL & 1) * 256 + mt * 64 + lane] = dacc[mt];
        if (j < 4) scr[((j + 3) & 7) * 512 + ntL * 64 + lane] = aacc;
      }
      __syncthreads();
      if (!khalf) {
        const int n = j * 64 + ntL * 16 + l15, kqG = n >> 3, jn = n & 7;
        #pragma unroll
        for (int mt = 0; mt < 4; ++mt) {
          f32x4 o = scr[slotWU * 512 + (ntL & 1) * 256 + mt * 64 + lane];
          #pragma unroll
          for (int r = 0; r < 4; ++r) {
            float g = lrelu(dacc[mt][r] + o[r] + birD);
            g1F[((size_t)kqG * 64 + mt * 16 + quad * 4 + r) * 8 + jn] = (_Float16)g;
          }
        }
        if (j < 4) {
          f32x4 o = scr[((j + 3) & 7) * 512 + ntL * 64 + lane];
          #pragma unroll
          for (int r = 0; r < 4; ++r) {
            float a = lrelu(aacc[r] + o[r] + ba1r) * wa3r;
            a += __shfl_xor(a, 1); a += __shfl_xor(a, 2);
            a += __shfl_xor(a, 4); a += __shfl_xor(a, 8);
            if (l15 == 0) zarr[j * 64 + ntL * 16 + quad * 4 + r] = a;
          }
        }
      }
    }
    __syncthreads();

    // ---- publish own G1 slice (+z) ----
    {
      f32x4 v = ((const f32x4*)g1F)[j * 512 + tid];
      st128((f32x4*)g1p + j * 512 + tid, v);
      if (j < 4 && tid < 64) stf(zp + j * 64 + tid, zarr[j * 64 + tid]);
    }
    vwait();
    __syncthreads();
    if (tid == 0) stu(gfl + j, (u32)(t + 1));

    // ---- gather peer G1 slices; wave j does cross-level plumbing ----
    if (wave != j) {
      poll1(gfl + wave, (u32)(t + 1));
      const f32x4* src = (const f32x4*)g1p + wave * 512;
      f32x4 g4[8];
      #pragma unroll
      for (int it = 0; it < 8; ++it) g4[it] = ld128(src + it * 64 + lane);
      float zv = 0.0f;
      if (wave < 4) zv = ldf(zp + wave * 64 + lane);
      vwait();
      #pragma unroll
      for (int it = 0; it < 8; ++it) ((f32x4*)g1F)[wave * 512 + it * 64 + lane] = g4[it];
      if (wave < 4) zarr[wave * 64 + lane] = zv;
    } else {
      if (level >= 2) {
        u32 need = (u32)((t + 2 <= SS) ? (t + 2) : SS);
        poll8(hflP, need, lane);
        float nmv = ldf(nmR + (size_t)((t + 1 < SS) ? (t + 1) : (SS - 1)) * 64 + lane);
        float hvv = ldf(hvR + (size_t)t * 64 + lane);
        vwait();
        nmA[lane] = nmv; hvA[lane] = hvv;
      } else {
        float mv = maskT[(size_t)t * 64 + lane];
        nmA[lane] = mv; hvA[lane] = mv;
      }
    }
    __syncthreads();

    // ---- xt[t+1] DMA (off critical path; drained at step end) ----
    if (t + 1 < SS) {
      const _Float16* src = xsrc + (size_t)(t + 1) * BB * DH;
      #pragma unroll
      for (int c = 0; c < 4; ++c) {
        int ub = wave * 256 + c * 64;
        dma16(src + (size_t)(ub + lane) * 8, bufH + (size_t)ub * 8);
      }
    }
    // ---- gates (wave 0) ----
    if (wave == 0) {
      int s = lane;
      float z   = bA3v + zarr[s] + zarr[64 + s] + zarr[128 + s] + zarr[192 + s];
      float nm0 = fminf(fmaxf(0.2f * z + 0.5f, 0.0f), 1.0f);
      float pm  = (level >= 2 && t + 1 >= SS) ? 1.0f : nmA[s];
      float phv = hvA[s];
      float lv  = (t == SS - 1) ? 1.0f : 0.0f;
      float nm  = (1.0f - lv) * (pm * phv * nm0);
      float hvp = gHv[s], omn = 1.0f - nm;
      float both = pm * phv * omn * hvp;
      float xo   = pm * phv * (nm + omn * (1.0f - hvp));
      float ho   = (1.0f - pm * phv) * omn * hvp;
      float hv   = both + xo + ho;
      gB[s] = both; gX[s] = xo; gH[s] = ho; gHv[s] = hv;
      if (level < 7) {
        stf(nmW + (size_t)t * 64 + s, nm);
        stf(hvW + (size_t)t * 64 + s, hv);
      }
    }
    __syncthreads();

    // ---- H: full h1 = lrelu(G1@W1+b1) (replicated); combine in place ----
    f32x4 c1[2][4] = {};
    #pragma unroll
    for (int kt = 0; kt < 16; ++kt) {
      int kq = kt * 4 + quad;
      f16x8 ag[4];
      #pragma unroll
      for (int mt = 0; mt < 4; ++mt)
        ag[mt] = *(const f16x8*)(g1F + ((size_t)kq * 64 + mt * 16 + l15) * 8);
      #pragma unroll
      for (int h2 = 0; h2 < 2; ++h2)
        #pragma unroll
        for (int mt = 0; mt < 4; ++mt)
          c1[h2][mt] = __builtin_amdgcn_mfma_f32_16x16x32_f16(ag[mt], b1f[h2][kt], c1[h2][mt], 0, 0, 0);
    }
    #pragma unroll
    for (int h2 = 0; h2 < 2; ++h2) {
      const int n = (wave * 2 + h2) * 16 + l15, kqc = n >> 3, jc = n & 7;
      const float b1r = h2 ? b1r1 : b1r0;
      #pragma unroll
      for (int mt = 0; mt < 4; ++mt)
        #pragma unroll
        for (int r = 0; r < 4; ++r) {
          int s = mt * 16 + quad * 4 + r;
          float h1  = lrelu(c1[h2][mt][r] + b1r);
          float xtv = (float)bufX[((size_t)kqc * 64 + s) * 8 + jc];
          float hn  = gB[s] * h1 + gX[s] * xtv + gH[s] * hreg[h2][mt][r];
          hreg[h2][mt][r] = hn;
          bufX[((size_t)kqc * 64 + s) * 8 + jc] = (_Float16)hn;   // in place
          if (level == 7 && t == SS - 1) outp[(size_t)s * DH + n] = hn;
        }
    }
    __syncthreads();

    // ---- publish own h slice (cross-level) ----
    if (level < 7 && tid < 256) {
      f32x4 v = ((const f32x4*)bufX)[j * 256 + tid];
      st128((f32x4*)(hdst + (size_t)t * BB * DH) + j * 256 + tid, v);
    }
    vwait();                 // drains h publish + nm/hv + xt DMA (all waves)
    __syncthreads();
    if (level < 7 && tid == 0) stu(hfl + j, (u32)(t + 1));
  }
}

// ---------------------------------------------------------------------------
extern "C" void kernel_launch(void* const* d_in, const int* in_sizes, int n_in,
                              void* d_out, int out_size, void* d_ws, size_t ws_size,
                              hipStream_t stream) {
  const float* x     = (const float*)d_in[0];
  const float* mask  = (const float*)d_in[1];
  const float* W_emb = (const float*)d_in[3];
  const float* b_emb = (const float*)d_in[4];
  const float* W     = (const float*)d_in[5];
  const float* U     = (const float*)d_in[6];
  const float* b     = (const float*)d_in[7];
  const float* W1    = (const float*)d_in[8];
  const float* b1    = (const float*)d_in[9];
  const float* WA1   = (const float*)d_in[10];
  const float* UA1   = (const float*)d_in[11];
  const float* bA1   = (const float*)d_in[12];
  const float* WA3   = (const float*)d_in[13];
  const float* bA3   = (const float*)d_in[14];
  char* ws = (char*)d_ws;

  if (ws_size < WS_NEEDED) return;

  zero_flags_k<<<1, 1024, 0, stream>>>((u32*)(ws + OFF_FLAGS));
  maskT_k<<<64, 256, 0, stream>>>(mask, (float*)(ws + OFF_MASKT));
  pack_weight_k<<<(DIN * DH + 255) / 256, 256, 0, stream>>>(W_emb, (_Float16*)(ws + OFF_WEMB), DIN, DH);
  pack_weight_k<<<(DH * DNN + 255) / 256, 256, 0, stream>>>(W, (_Float16*)(ws + OFF_W), DH, DNN);
  pack_weight_k<<<(DH * DNN + 255) / 256, 256, 0, stream>>>(U, (_Float16*)(ws + OFF_U), DH, DNN);
  pack_weight_k<<<(DNN * DH + 255) / 256, 256, 0, stream>>>(W1, (_Float16*)(ws + OFF_W1), DNN, DH);
  pack_weight_k<<<(DH * DA + 255) / 256, 256, 0, stream>>>(WA1, (_Float16*)(ws + OFF_WA1), DH, DA);
  pack_weight_k<<<(DH * DA + 255) / 256, 256, 0, stream>>>(UA1, (_Float16*)(ws + OFF_UA1), DH, DA);

  emb_k<<<64, 512, 0, stream>>>(x, b_emb, ws);
  pipe_k<<<56, 512, 0, stream>>>(b, b1, bA1, WA3, bA3, ws, (float*)d_out);
}

// Round 7
// 5281.120 us; speedup vs baseline: 2.1384x; 2.1343x over previous
//
#include <hip/hip_runtime.h>
#include <stdint.h>

// ---------------------------------------------------------------------------
// Encoder_Processor round 7: one-hop pipeline, 128-VGPR-safe by construction.
// 7 levels x 8 shards (56 WGs x 512 thr). Full xt + full h live in LDS
// (ping-pong); h is NEVER exchanged intra-level (each WG computes the full
// H = G1@W1 by STREAMING its W1 slice from L2 every step, double-buffered,
// overlapped with the G1 exchange). Only per-step fabric traffic: G1 slice
// broadcast (8KB publish, 7x8KB gather, parity double-buffered) + z partials
// + cross-level h slice. r5/r6 failed because full-W1-in-registers needed
// ~230 VGPRs vs the compiler's hard 128 -> per-step scratch/remat storm
// (VALUBusy 31% active, +64MB writes). This version peaks ~125 regs.
// ---------------------------------------------------------------------------

typedef _Float16 f16x8 __attribute__((ext_vector_type(8)));
typedef float    f32x4 __attribute__((ext_vector_type(4)));
typedef unsigned int u32;

static constexpr int SS = 256, BB = 64, DIN = 256, DH = 256, DNN = 512, DA = 64;

// workspace layout (bytes)
static constexpr size_t OFF_FLAGS = 0;                         // u32[2048]
static constexpr size_t OFF_MASKT = 8192;                      // f32 [t][s] 64KB
static constexpr size_t OFF_WEMB  = OFF_MASKT + 65536;
static constexpr size_t OFF_W     = OFF_WEMB + (size_t)DIN * DH * 2;
static constexpr size_t OFF_U     = OFF_W + (size_t)DH * DNN * 2;
static constexpr size_t OFF_W1    = OFF_U + (size_t)DH * DNN * 2;
static constexpr size_t OFF_WA1   = OFF_W1 + (size_t)DNN * DH * 2;
static constexpr size_t OFF_UA1   = OFF_WA1 + (size_t)DH * DA * 2;
static constexpr size_t OFF_NM    = OFF_UA1 + (size_t)DH * DA * 2;  // 8 x 64KB
static constexpr size_t SZ_NM     = (size_t)SS * BB * 4;
static constexpr size_t OFF_HV    = OFF_NM + 8 * SZ_NM;
static constexpr size_t OFF_G1    = OFF_HV + 8 * SZ_NM;        // 8 lvl x 2 par x 64KB
static constexpr size_t OFF_Z     = OFF_G1 + 8 * 2 * (size_t)BB * DNN * 2;  // 8 x 2 x 1KB
static constexpr size_t OFF_HB    = (size_t)4 << 20;           // 8 x 8MB f16 frag [t][kq][s]
static constexpr size_t SZ_HB     = (size_t)SS * BB * DH * 2;
static constexpr size_t WS_NEEDED = OFF_HB + 8 * SZ_HB;

__device__ __forceinline__ float lrelu(float v) { return v >= 0.0f ? v : 0.01f * v; }

// --- coherent (L1/L2-bypass, L3 point) asm ops; loads valid after vwait ----
__device__ __forceinline__ f32x4 ld128(const f32x4* p) {
  f32x4 r;
  asm volatile("global_load_dwordx4 %0, %1, off sc0 sc1" : "=v"(r) : "v"(p) : "memory");
  return r;
}
__device__ __forceinline__ void st128(f32x4* p, f32x4 v) {
  asm volatile("global_store_dwordx4 %0, %1, off sc0 sc1" :: "v"(p), "v"(v) : "memory");
}
__device__ __forceinline__ float ldf(const float* p) {
  float r;
  asm volatile("global_load_dword %0, %1, off sc0 sc1" : "=v"(r) : "v"(p) : "memory");
  return r;
}
__device__ __forceinline__ void stf(float* p, float v) {
  asm volatile("global_store_dword %0, %1, off sc0 sc1" :: "v"(p), "v"(v) : "memory");
}
__device__ __forceinline__ void stu(u32* p, u32 v) {
  asm volatile("global_store_dword %0, %1, off sc0 sc1" :: "v"(p), "v"(v) : "memory");
}
__device__ __forceinline__ u32 ldu(const u32* p) {
  u32 r;
  asm volatile("global_load_dword %0, %1, off sc0 sc1\n\ts_waitcnt vmcnt(0)"
               : "=v"(r) : "v"(p) : "memory");
  return r;
}
__device__ __forceinline__ void vwait() { asm volatile("s_waitcnt vmcnt(0)" ::: "memory"); }

// PLAIN cacheable 16B load (L2-hot weight streaming)
__device__ __forceinline__ f16x8 ld128p(const void* p) {
  f16x8 r;
  asm volatile("global_load_dwordx4 %0, %1, off" : "=v"(r) : "v"(p) : "memory");
  return r;
}
// waitcnt that LAUNDERS 8 in-flight frags: ties their values to the wait so
// the compiler cannot hoist MFMA consumers above it.
__device__ __forceinline__ void vwait8(f16x8& a0, f16x8& a1, f16x8& a2, f16x8& a3,
                                       f16x8& a4, f16x8& a5, f16x8& a6, f16x8& a7) {
  asm volatile("s_waitcnt vmcnt(0)"
               : "+v"(a0), "+v"(a1), "+v"(a2), "+v"(a3),
                 "+v"(a4), "+v"(a5), "+v"(a6), "+v"(a7) :: "memory");
}

__device__ __forceinline__ void poll1(const u32* p, u32 need) {
  #pragma nounroll
  for (int g = 0; g < (1 << 17); ++g) { if (ldu(p) >= need) return; }
}
__device__ __forceinline__ void poll8(const u32* base, u32 need, int lane) {
  #pragma nounroll
  for (int g = 0; g < (1 << 17); ++g) {
    u32 v = ldu(base + (lane & 7));
    if (__all((int)(v >= need))) return;
  }
}

// async global->LDS DMA, 16B/lane; lds base must be wave-uniform
__device__ __forceinline__ void dma16(const _Float16* g, _Float16* l) {
  auto* gp = (const __attribute__((address_space(1))) u32*)(uintptr_t)g;
  auto* lp = (__attribute__((address_space(3))) u32*)(uintptr_t)l;
  __builtin_amdgcn_global_load_lds(gp, lp, 16, 0, 0);
}

// ---------------------------------------------------------------------------
__global__ void zero_flags_k(u32* f) { f[threadIdx.x] = 0u; f[threadIdx.x + 1024] = 0u; }

__global__ void maskT_k(const float* __restrict__ mask, float* __restrict__ mT) {
  int idx = blockIdx.x * 256 + threadIdx.x;
  int t = idx >> 6, s = idx & 63;
  mT[idx] = mask[(size_t)s * SS + t];
}

// pack fp32 row-major [K][N] into f16 MFMA B-frag order
__global__ void pack_weight_k(const float* __restrict__ src, _Float16* __restrict__ dst,
                              int K, int N) {
  int idx = blockIdx.x * 256 + threadIdx.x;
  if (idx >= K * N) return;
  int k = idx / N, n = idx - k * N;
  int kt = k >> 5, q = (k >> 3) & 3, jj = k & 7;
  int nt = n >> 4, l = n & 15;
  size_t p = (((size_t)(kt * (N >> 4) + nt) * 4 + q) * 16 + l) * 8 + jj;
  dst[p] = (_Float16)src[idx];
}

// ---------------------------------------------------------------------------
// embedding: xe = x@W_emb + b_emb -> level-0 h buffer, frag-linear f16
// ---------------------------------------------------------------------------
__global__ __launch_bounds__(512, 2) void emb_k(const float* __restrict__ xin,
                                                const float* __restrict__ b_emb,
                                                char* __restrict__ ws) {
  const int tid = threadIdx.x, wave = tid >> 6, lane = tid & 63;
  const int l15 = lane & 15, quad = lane >> 4;
  const _Float16* Wp = (const _Float16*)(ws + OFF_WEMB);
  _Float16* xe = (_Float16*)(ws + OFF_HB);

  f16x8 bE[16];
  #pragma unroll
  for (int kt = 0; kt < 8; ++kt)
    #pragma unroll
    for (int i = 0; i < 2; ++i)
      bE[kt * 2 + i] = *(const f16x8*)(Wp + (((size_t)(kt * 16 + (wave * 2 + i)) * 4 + quad) * 16 + l15) * 8);
  float ber[2] = { b_emb[(wave * 2) * 16 + l15], b_emb[(wave * 2 + 1) * 16 + l15] };

  __shared__ __align__(16) _Float16 xtF[32 * 65 * 8];
  __shared__ __align__(16) _Float16 oF[32 * 65 * 8];

  for (int tt = 0; tt < 4; ++tt) {
    const int t = (int)blockIdx.x + 64 * tt;
    #pragma unroll
    for (int c = 0; c < 4; ++c) {
      int u = tid + 512 * c, s = u >> 5, kg = u & 31;
      const float* src = xin + ((size_t)s * SS + t) * DIN + kg * 8;
      f32x4 v0 = *(const f32x4*)src, v1 = *(const f32x4*)(src + 4);
      f16x8 p;
      p[0]=(_Float16)v0[0]; p[1]=(_Float16)v0[1]; p[2]=(_Float16)v0[2]; p[3]=(_Float16)v0[3];
      p[4]=(_Float16)v1[0]; p[5]=(_Float16)v1[1]; p[6]=(_Float16)v1[2]; p[7]=(_Float16)v1[3];
      *(f16x8*)(xtF + ((size_t)kg * 65 + s) * 8) = p;
    }
    __syncthreads();
    f32x4 acc[2][4] = {};
    #pragma unroll
    for (int kt = 0; kt < 8; ++kt) {
      f16x8 ax[4];
      #pragma unroll
      for (int mt = 0; mt < 4; ++mt)
        ax[mt] = *(const f16x8*)(xtF + (((size_t)(kt * 4 + quad)) * 65 + (mt * 16 + l15)) * 8);
      #pragma unroll
      for (int i = 0; i < 2; ++i)
        #pragma unroll
        for (int mt = 0; mt < 4; ++mt)
          acc[i][mt] = __builtin_amdgcn_mfma_f32_16x16x32_f16(ax[mt], bE[kt * 2 + i], acc[i][mt], 0, 0, 0);
    }
    #pragma unroll
    for (int i = 0; i < 2; ++i) {
      int n = (wave * 2 + i) * 16 + l15;
      int kq = n >> 3, jn = n & 7;
      #pragma unroll
      for (int mt = 0; mt < 4; ++mt)
        #pragma unroll
        for (int r = 0; r < 4; ++r) {
          int s = mt * 16 + quad * 4 + r;
          oF[((size_t)kq * 65 + s) * 8 + jn] = (_Float16)(acc[i][mt][r] + ber[i]);
        }
    }
    __syncthreads();
    #pragma unroll
    for (int c = 0; c < 4; ++c) {
      int u = tid + 512 * c, kq = u >> 6, s = u & 63;
      f32x4 v = *(const f32x4*)(oF + ((size_t)kq * 65 + s) * 8);
      *((f32x4*)(xe + (((size_t)t * 32 + kq) * 64 + s) * 8)) = v;
    }
    __syncthreads();
  }
}

// ---------------------------------------------------------------------------
// pipeline: 56 WGs (7 levels x 8 shards) x 512 thr
// ---------------------------------------------------------------------------
__global__ __launch_bounds__(512, 1) void pipe_k(
    const float* __restrict__ b_in, const float* __restrict__ b1v,
    const float* __restrict__ bA1, const float* __restrict__ WA3,
    const float* __restrict__ bA3, char* __restrict__ ws,
    float* __restrict__ outp) {
  const int level = 1 + ((int)blockIdx.x >> 3);
  const int j     = (int)blockIdx.x & 7;
  const int tid   = threadIdx.x, wave = tid >> 6, lane = tid & 63;
  const int l15   = lane & 15, quad = lane >> 4;
  const int mh    = wave >> 2, ntL = wave & 3;   // D roles: m-half, n-tile

  u32* flags = (u32*)(ws + OFF_FLAGS);
  u32* gfl   = flags + level * 16;
  u32* hfl   = flags + 256 + level * 16;
  u32* hflP  = flags + 256 + (level - 1) * 16;

  const _Float16* Wp   = (const _Float16*)(ws + OFF_W);
  const _Float16* Up   = (const _Float16*)(ws + OFF_U);
  const _Float16* W1p  = (const _Float16*)(ws + OFF_W1);
  const _Float16* WA1p = (const _Float16*)(ws + OFF_WA1);
  const _Float16* UA1p = (const _Float16*)(ws + OFF_UA1);
  const float*    maskT = (const float*)(ws + OFF_MASKT);

  const _Float16* xsrc = (const _Float16*)(ws + OFF_HB) + (size_t)(level - 1) * SS * BB * DH;
  _Float16* hdst = (level < 7) ? (_Float16*)(ws + OFF_HB) + (size_t)level * SS * BB * DH : nullptr;
  _Float16* g1g  = (_Float16*)(ws + OFF_G1) + (size_t)level * 2 * BB * DNN;
  float*    zg   = (float*)(ws + OFF_Z) + (size_t)level * 512;
  float*    nmW  = (float*)(ws + OFF_NM + (size_t)level * SZ_NM);
  float*    hvW  = (float*)(ws + OFF_HV + (size_t)level * SZ_NM);
  const float* nmR = (const float*)(ws + OFF_NM + (size_t)(level - 1) * SZ_NM);
  const float* hvR = (const float*)(ws + OFF_HV + (size_t)(level - 1) * SZ_NM);

  // --- D weights resident (64 VGPR): n-tile j*4+ntL, full K ---
  f16x8 bW[8], bU[8];
  #pragma unroll
  for (int kt = 0; kt < 8; ++kt) {
    bW[kt] = *(const f16x8*)(Wp + (((size_t)(kt * 32 + j * 4 + ntL) * 4 + quad) * 16 + l15) * 8);
    bU[kt] = *(const f16x8*)(Up + (((size_t)(kt * 32 + j * 4 + ntL) * 4 + quad) * 16 + l15) * 8);
  }
  const float birD = b_in[j * 64 + ntL * 16 + l15];
  const float b1r0 = b1v[(wave * 2) * 16 + l15];
  const float b1r1 = b1v[(wave * 2 + 1) * 16 + l15];
  const float ba1r = bA1[(j & 3) * 16 + l15];
  const float wa3r = WA3[(j & 3) * 16 + l15];
  const float bA3v = bA3[0];

  // --- LDS (~146KB) ---
  __shared__ __align__(16) _Float16 bufA[32 * 64 * 8];   // 32KB ping
  __shared__ __align__(16) _Float16 bufB[32 * 64 * 8];   // 32KB pong
  __shared__ __align__(16) _Float16 g1F[64 * 64 * 8];    // 64KB full G1
  __shared__ __align__(16) _Float16 waF[16 * 64 * 8];    // 16KB action b-frags
  __shared__ float zarr[256], nmA[64], hvA[64];
  __shared__ float gB[64], gX[64], gH[64], gHv[64];

  if (j < 4) {
    for (int u = tid; u < 1024; u += 512) {
      int ktm = u >> 6, lu = u & 63, kt = ktm >> 1, m = ktm & 1;
      const _Float16* sp = (m ? UA1p : WA1p) +
          (((size_t)(kt * 4 + j) * 4 + (lu >> 4)) * 16 + (lu & 15)) * 8;
      *(f16x8*)(waF + (size_t)u * 8) = *(const f16x8*)sp;
    }
  }
  #pragma unroll
  for (int c = 0; c < 4; ++c) ((f32x4*)bufB)[tid + 512 * c] = f32x4{0.f, 0.f, 0.f, 0.f};
  if (tid < 64) gHv[tid] = 0.0f;

  // prologue: stage xt[0] into bufA
  if (level >= 2 && wave == 0) poll8(hflP, 1, lane);
  __syncthreads();
  #pragma unroll
  for (int c = 0; c < 4; ++c) {
    int ub = wave * 256 + c * 64;
    dma16(xsrc + (size_t)(ub + lane) * 8, bufA + (size_t)ub * 8);
  }
  vwait();
  __syncthreads();

  for (int t = 0; t < SS; ++t) {
    const int par = t & 1;
    _Float16* bufX = par ? bufB : bufA;   // xt[t] -> becomes h[t] in place
    _Float16* bufH = par ? bufA : bufB;   // h[t-1] -> becomes xt[t+1] (DMA)
    _Float16* g1p  = g1g + (size_t)par * BB * DNN;
    float*    zp   = zg + par * 256;

    // ---- D: G1 n-tile (full K) + action partials ----
    {
      f32x4 dacc[2] = {};
      f32x4 aacc[2] = {};
      #pragma unroll
      for (int kt = 0; kt < 8; ++kt) {
        int kq = kt * 4 + quad;
        f16x8 ax0 = *(const f16x8*)(bufX + ((size_t)kq * 64 + (2 * mh) * 16 + l15) * 8);
        f16x8 ax1 = *(const f16x8*)(bufX + ((size_t)kq * 64 + (2 * mh + 1) * 16 + l15) * 8);
        f16x8 ah0 = *(const f16x8*)(bufH + ((size_t)kq * 64 + (2 * mh) * 16 + l15) * 8);
        f16x8 ah1 = *(const f16x8*)(bufH + ((size_t)kq * 64 + (2 * mh + 1) * 16 + l15) * 8);
        dacc[0] = __builtin_amdgcn_mfma_f32_16x16x32_f16(ax0, bW[kt], dacc[0], 0, 0, 0);
        dacc[1] = __builtin_amdgcn_mfma_f32_16x16x32_f16(ax1, bW[kt], dacc[1], 0, 0, 0);
        dacc[0] = __builtin_amdgcn_mfma_f32_16x16x32_f16(ah0, bU[kt], dacc[0], 0, 0, 0);
        dacc[1] = __builtin_amdgcn_mfma_f32_16x16x32_f16(ah1, bU[kt], dacc[1], 0, 0, 0);
        if (j < 4 && ntL == 0) {
          f16x8 bWa = *(const f16x8*)(waF + ((size_t)(kt * 2) * 64 + lane) * 8);
          f16x8 bUa = *(const f16x8*)(waF + ((size_t)(kt * 2 + 1) * 64 + lane) * 8);
          aacc[0] = __builtin_amdgcn_mfma_f32_16x16x32_f16(ax0, bWa, aacc[0], 0, 0, 0);
          aacc[0] = __builtin_amdgcn_mfma_f32_16x16x32_f16(ah0, bUa, aacc[0], 0, 0, 0);
          aacc[1] = __builtin_amdgcn_mfma_f32_16x16x32_f16(ax1, bWa, aacc[1], 0, 0, 0);
          aacc[1] = __builtin_amdgcn_mfma_f32_16x16x32_f16(ah1, bUa, aacc[1], 0, 0, 0);
        }
      }
      const int n = j * 64 + ntL * 16 + l15, kqG = n >> 3, jn = n & 7;
      #pragma unroll
      for (int i = 0; i < 2; ++i)
        #pragma unroll
        for (int r = 0; r < 4; ++r) {
          int s = (2 * mh + i) * 16 + quad * 4 + r;
          g1F[((size_t)kqG * 64 + s) * 8 + jn] = (_Float16)lrelu(dacc[i][r] + birD);
        }
      if (j < 4 && ntL == 0) {
        #pragma unroll
        for (int i = 0; i < 2; ++i)
          #pragma unroll
          for (int r = 0; r < 4; ++r) {
            float a = lrelu(aacc[i][r] + ba1r) * wa3r;
            a += __shfl_xor(a, 1); a += __shfl_xor(a, 2);
            a += __shfl_xor(a, 4); a += __shfl_xor(a, 8);
            if (l15 == 0) zarr[j * 64 + (2 * mh + i) * 16 + quad * 4 + r] = a;
          }
      }
    }
    __syncthreads();

    // ---- publish own G1 slice (+z) ----
    {
      f32x4 v = ((const f32x4*)g1F)[j * 512 + tid];
      st128((f32x4*)g1p + j * 512 + tid, v);
      if (j < 4 && tid < 64) stf(zp + j * 64 + tid, zarr[j * 64 + tid]);
    }
    vwait();
    __syncthreads();
    if (tid == 0) stu(gfl + j, (u32)(t + 1));

    // ---- gather peer G1 slices; wave j does cross-level plumbing ----
    if (wave != j) {
      poll1(gfl + wave, (u32)(t + 1));
      const f32x4* src = (const f32x4*)g1p + wave * 512;
      f32x4 g4[8];
      #pragma unroll
      for (int it = 0; it < 8; ++it) g4[it] = ld128(src + it * 64 + lane);
      float zv = 0.0f;
      if (wave < 4) zv = ldf(zp + wave * 64 + lane);
      vwait();
      #pragma unroll
      for (int it = 0; it < 8; ++it) ((f32x4*)g1F)[wave * 512 + it * 64 + lane] = g4[it];
      if (wave < 4) zarr[wave * 64 + lane] = zv;
    } else {
      if (level >= 2) {
        u32 need = (u32)((t + 2 <= SS) ? (t + 2) : SS);
        poll8(hflP, need, lane);
        float nmv = ldf(nmR + (size_t)((t + 1 < SS) ? (t + 1) : (SS - 1)) * 64 + lane);
        float hvv = ldf(hvR + (size_t)t * 64 + lane);
        vwait();
        nmA[lane] = nmv; hvA[lane] = hvv;
      } else {
        float mv = maskT[(size_t)t * 64 + lane];
        nmA[lane] = mv; hvA[lane] = mv;
      }
    }
    __syncthreads();

    // ---- gates (wave 0) ----
    if (wave == 0) {
      int s = lane;
      float z   = bA3v + zarr[s] + zarr[64 + s] + zarr[128 + s] + zarr[192 + s];
      float nm0 = fminf(fmaxf(0.2f * z + 0.5f, 0.0f), 1.0f);
      float pm  = (level >= 2 && t + 1 >= SS) ? 1.0f : nmA[s];
      float phv = hvA[s];
      float lv  = (t == SS - 1) ? 1.0f : 0.0f;
      float nm  = (1.0f - lv) * (pm * phv * nm0);
      float hvp = gHv[s], omn = 1.0f - nm;
      float both = pm * phv * omn * hvp;
      float xo   = pm * phv * (nm + omn * (1.0f - hvp));
      float ho   = (1.0f - pm * phv) * omn * hvp;
      float hv   = both + xo + ho;
      gB[s] = both; gX[s] = xo; gH[s] = ho; gHv[s] = hv;
      if (level < 7) {
        stf(nmW + (size_t)t * 64 + s, nm);
        stf(hvW + (size_t)t * 64 + s, hv);
      }
    }
    __syncthreads();

    // ---- H: full h1 = lrelu(G1@W1+b1), W1 STREAMED (dbuf batches of 8) ----
    f32x4 c1[2][4] = {};
    {
      f16x8 s0[8], s1[8];
      #pragma unroll
      for (int i = 0; i < 4; ++i) {   // batch 0: kt 0..3, nt {2w, 2w+1}
        s0[2 * i]     = ld128p(W1p + (((size_t)(i * 16 + wave * 2) * 4 + quad) * 16 + l15) * 8);
        s0[2 * i + 1] = ld128p(W1p + (((size_t)(i * 16 + wave * 2 + 1) * 4 + quad) * 16 + l15) * 8);
      }
      #pragma unroll
      for (int b = 0; b < 4; ++b) {
        f16x8* cur = (b & 1) ? s1 : s0;
        f16x8* nxt = (b & 1) ? s0 : s1;
        vwait8(cur[0], cur[1], cur[2], cur[3], cur[4], cur[5], cur[6], cur[7]);
        if (b < 3) {
          #pragma unroll
          for (int i = 0; i < 4; ++i) {
            int kt = (b + 1) * 4 + i;
            nxt[2 * i]     = ld128p(W1p + (((size_t)(kt * 16 + wave * 2) * 4 + quad) * 16 + l15) * 8);
            nxt[2 * i + 1] = ld128p(W1p + (((size_t)(kt * 16 + wave * 2 + 1) * 4 + quad) * 16 + l15) * 8);
          }
        }
        #pragma unroll
        for (int i = 0; i < 4; ++i) {
          int kq = (b * 4 + i) * 4 + quad;
          f16x8 ag[4];
          #pragma unroll
          for (int mt = 0; mt < 4; ++mt)
            ag[mt] = *(const f16x8*)(g1F + ((size_t)kq * 64 + mt * 16 + l15) * 8);
          #pragma unroll
          for (int mt = 0; mt < 4; ++mt) {
            c1[0][mt] = __builtin_amdgcn_mfma_f32_16x16x32_f16(ag[mt], cur[2 * i], c1[0][mt], 0, 0, 0);
            c1[1][mt] = __builtin_amdgcn_mfma_f32_16x16x32_f16(ag[mt], cur[2 * i + 1], c1[1][mt], 0, 0, 0);
          }
        }
      }
    }
    // ---- combine: h = gB*h1 + gX*xt + gH*h_tm1 (all f16 LDS, in place) ----
    #pragma unroll
    for (int h2 = 0; h2 < 2; ++h2) {
      const int n = (wave * 2 + h2) * 16 + l15, kqc = n >> 3, jc = n & 7;
      const float b1r = h2 ? b1r1 : b1r0;
      #pragma unroll
      for (int mt = 0; mt < 4; ++mt)
        #pragma unroll
        for (int r = 0; r < 4; ++r) {
          int s = mt * 16 + quad * 4 + r;
          float h1  = lrelu(c1[h2][mt][r] + b1r);
          float xtv = (float)bufX[((size_t)kqc * 64 + s) * 8 + jc];
          float hpv = (float)bufH[((size_t)kqc * 64 + s) * 8 + jc];
          float hn  = gB[s] * h1 + gX[s] * xtv + gH[s] * hpv;
          bufX[((size_t)kqc * 64 + s) * 8 + jc] = (_Float16)hn;
          if (level == 7 && t == SS - 1) outp[(size_t)s * DH + n] = hn;
        }
    }
    __syncthreads();   // combine writes done; bufH reads done

    // ---- xt[t+1] DMA into bufH + publish own h slice ----
    if (t + 1 < SS) {
      const _Float16* src = xsrc + (size_t)(t + 1) * BB * DH;
      #pragma unroll
      for (int c = 0; c < 4; ++c) {
        int ub = wave * 256 + c * 64;
        dma16(src + (size_t)(ub + lane) * 8, bufH + (size_t)ub * 8);
      }
    }
    if (level < 7 && tid < 256) {
      f32x4 v = ((const f32x4*)bufX)[j * 256 + tid];
      st128((f32x4*)(hdst + (size_t)t * BB * DH) + j * 256 + tid, v);
    }
    vwait();
    __syncthreads();
    if (level < 7 && tid == 0) stu(hfl + j, (u32)(t + 1));
  }
}

// ---------------------------------------------------------------------------
extern "C" void kernel_launch(void* const* d_in, const int* in_sizes, int n_in,
                              void* d_out, int out_size, void* d_ws, size_t ws_size,
                              hipStream_t stream) {
  const float* x     = (const float*)d_in[0];
  const float* mask  = (const float*)d_in[1];
  const float* W_emb = (const float*)d_in[3];
  const float* b_emb = (const float*)d_in[4];
  const float* W     = (const float*)d_in[5];
  const float* U     = (const float*)d_in[6];
  const float* b     = (const float*)d_in[7];
  const float* W1    = (const float*)d_in[8];
  const float* b1    = (const float*)d_in[9];
  const float* WA1   = (const float*)d_in[10];
  const float* UA1   = (const float*)d_in[11];
  const float* bA1   = (const float*)d_in[12];
  const float* WA3   = (const float*)d_in[13];
  const float* bA3   = (const float*)d_in[14];
  char* ws = (char*)d_ws;

  if (ws_size < WS_NEEDED) return;

  zero_flags_k<<<1, 1024, 0, stream>>>((u32*)(ws + OFF_FLAGS));
  maskT_k<<<64, 256, 0, stream>>>(mask, (float*)(ws + OFF_MASKT));
  pack_weight_k<<<(DIN * DH + 255) / 256, 256, 0, stream>>>(W_emb, (_Float16*)(ws + OFF_WEMB), DIN, DH);
  pack_weight_k<<<(DH * DNN + 255) / 256, 256, 0, stream>>>(W, (_Float16*)(ws + OFF_W), DH, DNN);
  pack_weight_k<<<(DH * DNN + 255) / 256, 256, 0, stream>>>(U, (_Float16*)(ws + OFF_U), DH, DNN);
  pack_weight_k<<<(DNN * DH + 255) / 256, 256, 0, stream>>>(W1, (_Float16*)(ws + OFF_W1), DNN, DH);
  pack_weight_k<<<(DH * DA + 255) / 256, 256, 0, stream>>>(WA1, (_Float16*)(ws + OFF_WA1), DH, DA);
  pack_weight_k<<<(DH * DA + 255) / 256, 256, 0, stream>>>(UA1, (_Float16*)(ws + OFF_UA1), DH, DA);

  emb_k<<<64, 512, 0, stream>>>(x, b_emb, ws);
  pipe_k<<<56, 512, 0, stream>>>(b, b1, bA1, WA3, bA3, ws, (float*)d_out);
}